// Round 8
// baseline (293.482 us; speedup 1.0000x reference)
//
#include <hip/hip_runtime.h>
#include <hip/hip_fp16.h>

#define NCOL 64
#define KDIM 128
#define NB 512          // max coarse buckets (dst>>8, N<=131072)
#define CH 2048         // edges per partition chunk

typedef short bf16x8 __attribute__((ext_vector_type(8)));
typedef float f32x4 __attribute__((ext_vector_type(4)));
typedef float f32x2 __attribute__((ext_vector_type(2)));

__device__ __forceinline__ unsigned short f2bf(float f) {
    unsigned int u = __float_as_uint(f);
    return (unsigned short)((u + 0x7fffu + ((u >> 16) & 1u)) >> 16);
}
__device__ __forceinline__ float bflo(unsigned int u) { return __uint_as_float(u << 16); }
__device__ __forceinline__ float bfhi(unsigned int u) { return __uint_as_float(u & 0xffff0000u); }

// ---------------- K1: coarse bucket hist (LDS) + outcnt hist ----------------
__global__ __launch_bounds__(256) void coarse_hist(const int* __restrict__ src,
                                                   const int* __restrict__ dst,
                                                   int* __restrict__ outcnt,
                                                   int* __restrict__ bcnt, int E) {
    __shared__ int lh[NB];
    int tid = threadIdx.x;
    for (int i = tid; i < NB; i += 256) lh[i] = 0;
    __syncthreads();
    int i = blockIdx.x * blockDim.x + tid;
    int stride = gridDim.x * blockDim.x;
    for (int e = i; e < E; e += stride) {
        atomicAdd(&outcnt[src[e]], 1);
        atomicAdd(&lh[dst[e] >> 8], 1);
    }
    __syncthreads();
    for (int k = tid; k < NB; k += 256) {
        int c = lh[k];
        if (c) atomicAdd(&bcnt[k], c);
    }
}

// ---------------- K2: scan bucket counts -> bbase, bcur ----------------
__global__ __launch_bounds__(256) void bucket_scan(const int* __restrict__ bcnt,
                                                   int* __restrict__ bbase, int* __restrict__ bcur,
                                                   int* __restrict__ row_start, int N, int E) {
    __shared__ int wsum[8];
    int tid = threadIdx.x, lane = tid & 63, wv = tid >> 6;
    int a = bcnt[tid], b = bcnt[tid + 256];
    int ia = a, ib = b;
#pragma unroll
    for (int off = 1; off < 64; off <<= 1) {
        int t = __shfl_up(ia, off); if (lane >= off) ia += t;
        int u = __shfl_up(ib, off); if (lane >= off) ib += u;
    }
    if (lane == 63) { wsum[wv] = ia; wsum[4 + wv] = ib; }
    __syncthreads();
    if (tid == 0) { int run = 0; for (int i = 0; i < 8; ++i) { int t = wsum[i]; wsum[i] = run; run += t; } }
    __syncthreads();
    int ea = wsum[wv] + ia - a;
    int eb = wsum[4 + wv] + ib - b;
    bbase[tid] = ea; bcur[tid] = ea;
    bbase[tid + 256] = eb; bcur[tid + 256] = eb;
    if (tid == 0) row_start[N] = E;
}

// ---------------- K3: partition edges into coarse buckets (coalesced writes) ----------------
__global__ __launch_bounds__(256) void partition_kernel(
    const int* __restrict__ src, const int* __restrict__ dst,
    int* __restrict__ bcur, uint2* __restrict__ pairs, int E) {
    __shared__ int hist[NB];
    __shared__ int lbase[NB];
    __shared__ int gbase[NB];
    __shared__ int lcur[NB];
    __shared__ uint2 sp[CH];   // 16 KB
    __shared__ int wsum[8];

    int tid = threadIdx.x, lane = tid & 63, wv = tid >> 6;
    int c0 = blockIdx.x * CH;
    int cnt = min(CH, E - c0);

    for (int i = tid; i < NB; i += 256) hist[i] = 0;
    __syncthreads();
    for (int i = tid; i < cnt; i += 256)
        atomicAdd(&hist[dst[c0 + i] >> 8], 1);
    __syncthreads();

    {
        int a = hist[tid], b = hist[tid + 256];
        int ia = a, ib = b;
#pragma unroll
        for (int off = 1; off < 64; off <<= 1) {
            int t = __shfl_up(ia, off); if (lane >= off) ia += t;
            int u = __shfl_up(ib, off); if (lane >= off) ib += u;
        }
        if (lane == 63) { wsum[wv] = ia; wsum[4 + wv] = ib; }
        __syncthreads();
        if (tid == 0) { int run = 0; for (int i = 0; i < 8; ++i) { int t = wsum[i]; wsum[i] = run; run += t; } }
        __syncthreads();
        lbase[tid] = wsum[wv] + ia - a;
        lbase[tid + 256] = wsum[4 + wv] + ib - b;
    }
    __syncthreads();

    for (int k = tid; k < NB; k += 256) {
        int c = hist[k];
        gbase[k] = c ? atomicAdd(&bcur[k], c) : 0;
        lcur[k] = lbase[k];
    }
    __syncthreads();

    for (int i = tid; i < cnt; i += 256) {
        int s = src[c0 + i], d = dst[c0 + i];
        int p = atomicAdd(&lcur[d >> 8], 1);
        sp[p] = make_uint2((unsigned)s, (unsigned)d);
    }
    __syncthreads();

    for (int i = tid; i < cnt; i += 256) {
        uint2 p = sp[i];
        int k = (int)(p.y >> 8);
        pairs[gbase[k] + (i - lbase[k])] = p;
    }
}

// ---------------- K4: fine counting sort, 512 bins (dst&255, src-half) ----------------
// row_start[d] = start of lo-src edges; row_mid[d] = start of hi-src edges.
__global__ __launch_bounds__(256) void fine_kernel(
    const uint2* __restrict__ pairs, const int* __restrict__ bbase,
    int* __restrict__ row_start, int* __restrict__ row_mid, int* __restrict__ ssrc,
    int E, int nbuck, int N, unsigned int Nhalf) {
    __shared__ int hist[512];
    __shared__ int cur[512];
    __shared__ int wsum[4];
    int k = blockIdx.x;
    int tid = threadIdx.x, lane = tid & 63, wv = tid >> 6;
    int b0 = bbase[k];
    int b1 = (k + 1 < nbuck) ? bbase[k + 1] : E;

    hist[tid] = 0; hist[tid + 256] = 0;
    __syncthreads();
    for (int i = b0 + tid; i < b1; i += 256) {
        uint2 p = pairs[i];
        atomicAdd(&hist[((p.y & 255u) << 1) | (p.x >= Nhalf)], 1);
    }
    __syncthreads();

    int lo = hist[2 * tid], hi = hist[2 * tid + 1];
    int x = lo + hi, inc = x;
#pragma unroll
    for (int off = 1; off < 64; off <<= 1) {
        int t = __shfl_up(inc, off); if (lane >= off) inc += t;
    }
    if (lane == 63) wsum[wv] = inc;
    __syncthreads();
    if (tid == 0) { int run = 0; for (int i = 0; i < 4; ++i) { int t = wsum[i]; wsum[i] = run; run += t; } }
    __syncthreads();
    int excl = wsum[wv] + inc - x;

    int baseLo = b0 + excl;
    int baseHi = baseLo + lo;
    int d = (k << 8) + tid;
    if (d < N) { row_start[d] = baseLo; row_mid[d] = baseHi; }
    cur[2 * tid] = baseLo;
    cur[2 * tid + 1] = baseHi;
    __syncthreads();

    for (int i = b0 + tid; i < b1; i += 256) {
        uint2 p = pairs[i];
        int key = ((p.y & 255u) << 1) | (p.x >= Nhalf);
        int pos = atomicAdd(&cur[key], 1);
        ssrc[pos] = (int)p.x;
    }
}

// ---------------- K5: MFMA dual GEMM; h stored fp8 e4m3 (HW cvt) column-strided ----------------
// hb8[row*16 + c16] byte ct = col ct*16+c16.
__global__ __launch_bounds__(256) void matmul_mfma(
    const float* __restrict__ feat, const float* __restrict__ W,
    const float* __restrict__ RW, const float* __restrict__ res_b,
    const int* __restrict__ outcnt,
    unsigned int* __restrict__ hb8, float* __restrict__ y, int N) {
    __shared__ bf16x8 Bf[2048];   // 32 KB
    int tid = threadIdx.x;
    for (int idx = tid; idx < 2048; idx += 256) {
        int mat = idx >> 10;
        int kc = (idx >> 8) & 3;
        int ct = (idx >> 6) & 3;
        int l = idx & 63;
        const float* Wp = mat ? RW : W;
        int kbase = kc * 32 + (l >> 4) * 8;
        int col = ct * 16 + (l & 15);
        bf16x8 t;
#pragma unroll
        for (int j = 0; j < 8; ++j)
            t[j] = (short)f2bf(Wp[(size_t)(kbase + j) * NCOL + col]);
        Bf[idx] = t;
    }
    __syncthreads();

    int lane = tid & 63;
    int wid = tid >> 6;
    int wave = blockIdx.x * 4 + wid;
    int nwaves = gridDim.x * 4;
    int ntiles = (N + 15) >> 4;
    int c16 = lane & 15, kg = lane >> 4;

    float rbv[4];
#pragma unroll
    for (int ct = 0; ct < 4; ++ct) rbv[ct] = res_b[ct * 16 + c16];

    for (int tile = wave; tile < ntiles; tile += nwaves) {
        int tb = tile << 4;
        f32x4 acch[4], accr[4];
#pragma unroll
        for (int ct = 0; ct < 4; ++ct) {
            acch[ct] = (f32x4){0.f, 0.f, 0.f, 0.f};
            accr[ct] = (f32x4){0.f, 0.f, 0.f, 0.f};
        }

        int arow = tb + c16; if (arow >= N) arow = N - 1;
        const float* fp = feat + (size_t)arow * KDIM + kg * 8;
#pragma unroll
        for (int kc = 0; kc < 4; ++kc) {
            float4 a0 = *(const float4*)(fp + kc * 32);
            float4 a1 = *(const float4*)(fp + kc * 32 + 4);
            bf16x8 af;
            af[0] = (short)f2bf(a0.x); af[1] = (short)f2bf(a0.y);
            af[2] = (short)f2bf(a0.z); af[3] = (short)f2bf(a0.w);
            af[4] = (short)f2bf(a1.x); af[5] = (short)f2bf(a1.y);
            af[6] = (short)f2bf(a1.z); af[7] = (short)f2bf(a1.w);
#pragma unroll
            for (int ct = 0; ct < 4; ++ct) {
                acch[ct] = __builtin_amdgcn_mfma_f32_16x16x32_bf16(
                    af, Bf[(kc * 4 + ct) * 64 + lane], acch[ct], 0, 0, 0);
                accr[ct] = __builtin_amdgcn_mfma_f32_16x16x32_bf16(
                    af, Bf[1024 + (kc * 4 + ct) * 64 + lane], accr[ct], 0, 0, 0);
            }
        }

        float nrm[4];
#pragma unroll
        for (int r = 0; r < 4; ++r) {
            int rw = tb + kg * 4 + r; if (rw >= N) rw = N - 1;
            nrm[r] = rsqrtf(fmaxf((float)outcnt[rw], 1.0f));
        }
#pragma unroll
        for (int r = 0; r < 4; ++r) {
            int row = tb + kg * 4 + r;
            if (row < N) {
                unsigned int p = 0;
                p = (unsigned int)__builtin_amdgcn_cvt_pk_fp8_f32(
                        acch[0][r] * nrm[r], acch[1][r] * nrm[r], (int)p, false);
                p = (unsigned int)__builtin_amdgcn_cvt_pk_fp8_f32(
                        acch[2][r] * nrm[r], acch[3][r] * nrm[r], (int)p, true);
#pragma unroll
                for (int ct = 0; ct < 4; ++ct)
                    y[(size_t)row * NCOL + ct * 16 + c16] = fmaxf(accr[ct][r] + rbv[ct], 0.0f);
                hb8[(size_t)row * 16 + c16] = p;
            }
        }
    }
}

// ---------------- gather helpers ----------------
// lane: e4 = lane>>4 (edge slot), dw = lane&15 (dword of 64B row).
// 8-edge masked steps per row, 2 rows (d0,d1) interleaved for MLP.
#define GATHER_ROW_STEP(eBase, eEnd, A0, A1, A2, A3)                                   \
    {                                                                                   \
        int e0 = (eBase) + e4, e1 = e0 + 4;                                             \
        int i0 = (e0 < (eEnd)) ? ssrc[e0] : -1;                                         \
        int i1 = (e1 < (eEnd)) ? ssrc[e1] : -1;                                         \
        unsigned int v0 = (i0 >= 0) ? hb8[(size_t)i0 * 16 + dw] : 0u;                   \
        unsigned int v1 = (i1 >= 0) ? hb8[(size_t)i1 * 16 + dw] : 0u;                   \
        f32x2 l0 = __builtin_amdgcn_cvt_pk_f32_fp8((int)v0, false);                     \
        f32x2 h0 = __builtin_amdgcn_cvt_pk_f32_fp8((int)v0, true);                      \
        f32x2 l1 = __builtin_amdgcn_cvt_pk_f32_fp8((int)v1, false);                     \
        f32x2 h1 = __builtin_amdgcn_cvt_pk_f32_fp8((int)v1, true);                      \
        A0 += l0[0] + l1[0]; A1 += l0[1] + l1[1];                                       \
        A2 += h0[0] + h1[0]; A3 += h0[1] + h1[1];                                       \
    }

// ---------------- K6a: gather lo-src half -> partial (bf16 packed, aliases pairs) ----------------
__global__ __launch_bounds__(256) void gather_lo(
    const int* __restrict__ row_start, const int* __restrict__ row_mid,
    const int* __restrict__ ssrc, const unsigned int* __restrict__ hb8,
    uint2* __restrict__ part, int N) {
    int tid = threadIdx.x, lane = tid & 63, wid = tid >> 6;
    int e4 = lane >> 4, dw = lane & 15;
    int wave = blockIdx.x * 4 + wid;
    int nwaves = gridDim.x * 4;

    for (int d0 = wave * 2; d0 < N; d0 += 2 * nwaves) {
        int d1 = d0 + 1;
        int a0 = row_start[d0], a1 = row_mid[d0];
        int b0 = 0, b1 = 0;
        if (d1 < N) { b0 = row_start[d1]; b1 = row_mid[d1]; }
        float A0 = 0.f, A1 = 0.f, A2 = 0.f, A3 = 0.f;
        float B0 = 0.f, B1 = 0.f, B2 = 0.f, B3 = 0.f;
        int nit = max((a1 - a0 + 7) >> 3, (b1 - b0 + 7) >> 3);
        for (int it = 0; it < nit; ++it) {
            GATHER_ROW_STEP(a0 + it * 8, a1, A0, A1, A2, A3)
            GATHER_ROW_STEP(b0 + it * 8, b1, B0, B1, B2, B3)
        }
#pragma unroll
        for (int off = 16; off <= 32; off <<= 1) {
            A0 += __shfl_xor(A0, off); A1 += __shfl_xor(A1, off);
            A2 += __shfl_xor(A2, off); A3 += __shfl_xor(A3, off);
            B0 += __shfl_xor(B0, off); B1 += __shfl_xor(B1, off);
            B2 += __shfl_xor(B2, off); B3 += __shfl_xor(B3, off);
        }
        if (e4 == 0) {
            uint2 p;
            p.x = ((unsigned)f2bf(A1) << 16) | f2bf(A0);
            p.y = ((unsigned)f2bf(A3) << 16) | f2bf(A2);
            part[(size_t)d0 * 16 + dw] = p;
        } else if (e4 == 1 && d1 < N) {
            uint2 p;
            p.x = ((unsigned)f2bf(B1) << 16) | f2bf(B0);
            p.y = ((unsigned)f2bf(B3) << 16) | f2bf(B2);
            part[(size_t)d1 * 16 + dw] = p;
        }
    }
}

// ---------------- K6b: gather hi-src half + partial + finalize + BN ----------------
__global__ __launch_bounds__(256) void gather_hi(
    const int* __restrict__ row_start, const int* __restrict__ row_mid,
    const int* __restrict__ ssrc, const unsigned int* __restrict__ hb8,
    const uint2* __restrict__ part, const float* __restrict__ b,
    float* __restrict__ y, float* __restrict__ stats, int N) {
    int tid = threadIdx.x, lane = tid & 63, wid = tid >> 6;
    int e4 = lane >> 4, dw = lane & 15;
    int wave = blockIdx.x * 4 + wid;
    int nwaves = gridDim.x * 4;

    float bc[4];
#pragma unroll
    for (int j = 0; j < 4; ++j) bc[j] = b[16 * j + dw];

    float bnsum[4] = {0.f, 0.f, 0.f, 0.f};
    float bnsq[4] = {0.f, 0.f, 0.f, 0.f};

    for (int d0 = wave * 2; d0 < N; d0 += 2 * nwaves) {
        int d1 = d0 + 1;
        int rsA = row_start[d0], a0 = row_mid[d0], a1 = row_start[d0 + 1];
        int rsB = 0, b0 = 0, b1 = 0;
        if (d1 < N) { rsB = a1; b0 = row_mid[d1]; b1 = row_start[d1 + 1]; }
        float A0 = 0.f, A1 = 0.f, A2 = 0.f, A3 = 0.f;
        float B0 = 0.f, B1 = 0.f, B2 = 0.f, B3 = 0.f;
        int nit = max((a1 - a0 + 7) >> 3, (b1 - b0 + 7) >> 3);
        for (int it = 0; it < nit; ++it) {
            GATHER_ROW_STEP(a0 + it * 8, a1, A0, A1, A2, A3)
            GATHER_ROW_STEP(b0 + it * 8, b1, B0, B1, B2, B3)
        }
#pragma unroll
        for (int off = 16; off <= 32; off <<= 1) {
            A0 += __shfl_xor(A0, off); A1 += __shfl_xor(A1, off);
            A2 += __shfl_xor(A2, off); A3 += __shfl_xor(A3, off);
            B0 += __shfl_xor(B0, off); B1 += __shfl_xor(B1, off);
            B2 += __shfl_xor(B2, off); B3 += __shfl_xor(B3, off);
        }

        int dd = -1;
        float c0, c1, c2, c3;
        int deg = 0;
        if (e4 == 0) {
            dd = d0; deg = a1 - rsA; c0 = A0; c1 = A1; c2 = A2; c3 = A3;
        } else if (e4 == 1 && d1 < N) {
            dd = d1; deg = b1 - rsB; c0 = B0; c1 = B1; c2 = B2; c3 = B3;
        }
        if (dd >= 0) {
            uint2 p = part[(size_t)dd * 16 + dw];
            c0 += bflo(p.x); c1 += bfhi(p.x);
            c2 += bflo(p.y); c3 += bfhi(p.y);
            float nd = rsqrtf(fmaxf((float)deg, 1.0f));
            float av[4] = {c0, c1, c2, c3};
#pragma unroll
            for (int j = 0; j < 4; ++j) {
                float* yp = &y[(size_t)dd * NCOL + 16 * j + dw];
                float v = fmaxf(av[j] * nd + bc[j], 0.f) + *yp;
                *yp = v;
                bnsum[j] += v;
                bnsq[j] += v * v;
            }
        }
    }

    // reduce BN partials across e4 groups, then block-reduce
#pragma unroll
    for (int j = 0; j < 4; ++j) {
#pragma unroll
        for (int off = 16; off <= 32; off <<= 1) {
            bnsum[j] += __shfl_xor(bnsum[j], off);
            bnsq[j] += __shfl_xor(bnsq[j], off);
        }
    }
    __shared__ float bnred[4][128];
    if (e4 == 0) {
#pragma unroll
        for (int j = 0; j < 4; ++j) {
            bnred[wid][16 * j + dw] = bnsum[j];
            bnred[wid][64 + 16 * j + dw] = bnsq[j];
        }
    }
    __syncthreads();
    if (tid < 128) {
        float v = bnred[0][tid] + bnred[1][tid] + bnred[2][tid] + bnred[3][tid];
        unsafeAtomicAdd(&stats[tid], v);
    }
}

// ---------------- K7: BN scale/shift ----------------
__global__ void bnparam_kernel(const float* __restrict__ gamma, const float* __restrict__ beta,
                               float* __restrict__ stats, float invN) {
    int c = threadIdx.x;
    float mean = stats[c] * invN;
    float var = stats[64 + c] * invN - mean * mean;
    float s = gamma[c] * rsqrtf(var + 1e-5f);
    stats[128 + c] = s;
    stats[192 + c] = beta[c] - mean * s;
}

// ---------------- K8: BN apply (in place, float4) ----------------
__global__ __launch_bounds__(256) void apply_kernel(float* __restrict__ y,
                                                    const float* __restrict__ stats, int total4) {
    int i = blockIdx.x * blockDim.x + threadIdx.x;
    int stride = gridDim.x * blockDim.x;
    float4* y4 = (float4*)y;
    for (; i < total4; i += stride) {
        float4 v = y4[i];
        int cbase = (i & 15) << 2;
        float4 s = *(const float4*)&stats[128 + cbase];
        float4 t = *(const float4*)&stats[192 + cbase];
        v.x = v.x * s.x + t.x;
        v.y = v.y * s.y + t.y;
        v.z = v.z * s.z + t.z;
        v.w = v.w * s.w + t.w;
        y4[i] = v;
    }
}

extern "C" void kernel_launch(void* const* d_in, const int* in_sizes, int n_in,
                              void* d_out, int out_size, void* d_ws, size_t ws_size,
                              hipStream_t stream) {
    const float* feat  = (const float*)d_in[0];
    const int*   src   = (const int*)d_in[1];
    const int*   dst   = (const int*)d_in[2];
    const float* W     = (const float*)d_in[3];
    const float* b     = (const float*)d_in[4];
    const float* RW    = (const float*)d_in[5];
    const float* rb    = (const float*)d_in[6];
    const float* gamma = (const float*)d_in[7];
    const float* beta  = (const float*)d_in[8];

    int N = in_sizes[0] / KDIM;
    int E = in_sizes[1];
    float* out = (float*)d_out;
    int nbuck = (N + 255) >> 8;   // assumes N <= 131072

    // workspace layout
    char* wsb = (char*)d_ws;
    unsigned int* hb8 = (unsigned int*)wsb;                wsb += (size_t)N * 16 * 4;
    uint2* pairs    = (uint2*)wsb;                         wsb += (size_t)E * 8;   // part aliases this
    int*   ssrc     = (int*)wsb;                           wsb += (size_t)E * 4;
    int*   row_start= (int*)wsb;                           wsb += (size_t)(N + 1) * 4;
    int*   row_mid  = (int*)wsb;                           wsb += (size_t)N * 4;
    int*   outcnt   = (int*)wsb;                           wsb += (size_t)N * 4;
    float* stats    = (float*)wsb;                         wsb += 256 * 4;
    int*   bcnt     = (int*)wsb;                           wsb += NB * 4;
    int*   bbase    = (int*)wsb;                           wsb += NB * 4;
    int*   bcur     = (int*)wsb;
    uint2* part     = pairs;   // pairs is dead after fine_kernel

    // zero outcnt | stats | bcnt (contiguous)
    hipMemsetAsync(outcnt, 0, ((size_t)N + 256 + NB) * 4, stream);

    coarse_hist<<<1024, 256, 0, stream>>>(src, dst, outcnt, bcnt, E);
    bucket_scan<<<1, 256, 0, stream>>>(bcnt, bbase, bcur, row_start, N, E);
    matmul_mfma<<<512, 256, 0, stream>>>(feat, W, RW, rb, outcnt, hb8, out, N);
    partition_kernel<<<(E + CH - 1) / CH, 256, 0, stream>>>(src, dst, bcur, pairs, E);
    fine_kernel<<<nbuck, 256, 0, stream>>>(pairs, bbase, row_start, row_mid, ssrc, E, nbuck, N,
                                           (unsigned int)(N / 2));
    gather_lo<<<2048, 256, 0, stream>>>(row_start, row_mid, ssrc, hb8, part, N);
    gather_hi<<<2048, 256, 0, stream>>>(row_start, row_mid, ssrc, hb8, part, b, out, stats, N);
    bnparam_kernel<<<1, 64, 0, stream>>>(gamma, beta, stats, 1.0f / (float)N);
    apply_kernel<<<2048, 256, 0, stream>>>(out, stats, (N * NCOL) / 4);
}

// Round 9
// 278.088 us; speedup vs baseline: 1.0554x; 1.0554x over previous
//
#include <hip/hip_runtime.h>
#include <hip/hip_fp16.h>

#define NCOL 64
#define KDIM 128
#define NB 512          // max coarse buckets (dst>>8, N<=131072)
#define CH 2048         // edges per partition chunk

typedef short bf16x8 __attribute__((ext_vector_type(8)));
typedef float f32x4 __attribute__((ext_vector_type(4)));
typedef float f32x2 __attribute__((ext_vector_type(2)));

__device__ __forceinline__ unsigned short f2bf(float f) {
    unsigned int u = __float_as_uint(f);
    return (unsigned short)((u + 0x7fffu + ((u >> 16) & 1u)) >> 16);
}

// ---------------- K1: coarse bucket hist (LDS) + outcnt hist ----------------
__global__ __launch_bounds__(256) void coarse_hist(const int* __restrict__ src,
                                                   const int* __restrict__ dst,
                                                   int* __restrict__ outcnt,
                                                   int* __restrict__ bcnt, int E) {
    __shared__ int lh[NB];
    int tid = threadIdx.x;
    for (int i = tid; i < NB; i += 256) lh[i] = 0;
    __syncthreads();
    int i = blockIdx.x * blockDim.x + tid;
    int stride = gridDim.x * blockDim.x;
    for (int e = i; e < E; e += stride) {
        atomicAdd(&outcnt[src[e]], 1);
        atomicAdd(&lh[dst[e] >> 8], 1);
    }
    __syncthreads();
    for (int k = tid; k < NB; k += 256) {
        int c = lh[k];
        if (c) atomicAdd(&bcnt[k], c);
    }
}

// ---------------- K2: scan bucket counts -> bbase, bcur ----------------
__global__ __launch_bounds__(256) void bucket_scan(const int* __restrict__ bcnt,
                                                   int* __restrict__ bbase, int* __restrict__ bcur,
                                                   int* __restrict__ row_start, int N, int E) {
    __shared__ int wsum[8];
    int tid = threadIdx.x, lane = tid & 63, wv = tid >> 6;
    int a = bcnt[tid], b = bcnt[tid + 256];
    int ia = a, ib = b;
#pragma unroll
    for (int off = 1; off < 64; off <<= 1) {
        int t = __shfl_up(ia, off); if (lane >= off) ia += t;
        int u = __shfl_up(ib, off); if (lane >= off) ib += u;
    }
    if (lane == 63) { wsum[wv] = ia; wsum[4 + wv] = ib; }
    __syncthreads();
    if (tid == 0) { int run = 0; for (int i = 0; i < 8; ++i) { int t = wsum[i]; wsum[i] = run; run += t; } }
    __syncthreads();
    int ea = wsum[wv] + ia - a;
    int eb = wsum[4 + wv] + ib - b;
    bbase[tid] = ea; bcur[tid] = ea;
    bbase[tid + 256] = eb; bcur[tid + 256] = eb;
    if (tid == 0) row_start[N] = E;
}

// ---------------- K3: partition edges into coarse buckets (coalesced writes) ----------------
__global__ __launch_bounds__(256) void partition_kernel(
    const int* __restrict__ src, const int* __restrict__ dst,
    int* __restrict__ bcur, uint2* __restrict__ pairs, int E) {
    __shared__ int hist[NB];
    __shared__ int lbase[NB];
    __shared__ int gbase[NB];
    __shared__ int lcur[NB];
    __shared__ uint2 sp[CH];   // 16 KB
    __shared__ int wsum[8];

    int tid = threadIdx.x, lane = tid & 63, wv = tid >> 6;
    int c0 = blockIdx.x * CH;
    int cnt = min(CH, E - c0);

    for (int i = tid; i < NB; i += 256) hist[i] = 0;
    __syncthreads();
    for (int i = tid; i < cnt; i += 256)
        atomicAdd(&hist[dst[c0 + i] >> 8], 1);
    __syncthreads();

    {
        int a = hist[tid], b = hist[tid + 256];
        int ia = a, ib = b;
#pragma unroll
        for (int off = 1; off < 64; off <<= 1) {
            int t = __shfl_up(ia, off); if (lane >= off) ia += t;
            int u = __shfl_up(ib, off); if (lane >= off) ib += u;
        }
        if (lane == 63) { wsum[wv] = ia; wsum[4 + wv] = ib; }
        __syncthreads();
        if (tid == 0) { int run = 0; for (int i = 0; i < 8; ++i) { int t = wsum[i]; wsum[i] = run; run += t; } }
        __syncthreads();
        lbase[tid] = wsum[wv] + ia - a;
        lbase[tid + 256] = wsum[4 + wv] + ib - b;
    }
    __syncthreads();

    for (int k = tid; k < NB; k += 256) {
        int c = hist[k];
        gbase[k] = c ? atomicAdd(&bcur[k], c) : 0;
        lcur[k] = lbase[k];
    }
    __syncthreads();

    for (int i = tid; i < cnt; i += 256) {
        int s = src[c0 + i], d = dst[c0 + i];
        int p = atomicAdd(&lcur[d >> 8], 1);
        sp[p] = make_uint2((unsigned)s, (unsigned)d);
    }
    __syncthreads();

    for (int i = tid; i < cnt; i += 256) {
        uint2 p = sp[i];
        int k = (int)(p.y >> 8);
        pairs[gbase[k] + (i - lbase[k])] = p;
    }
}

// ---------------- K4: fine counting sort within bucket -> ssrc + row_start ----------------
__global__ __launch_bounds__(256) void fine_kernel(
    const uint2* __restrict__ pairs, const int* __restrict__ bbase,
    int* __restrict__ row_start, int* __restrict__ ssrc, int E, int nbuck, int N) {
    __shared__ int hist[256];
    __shared__ int cur[256];
    __shared__ int wsum[4];
    int k = blockIdx.x;
    int tid = threadIdx.x, lane = tid & 63, wv = tid >> 6;
    int b0 = bbase[k];
    int b1 = (k + 1 < nbuck) ? bbase[k + 1] : E;

    hist[tid] = 0;
    __syncthreads();
    for (int i = b0 + tid; i < b1; i += 256)
        atomicAdd(&hist[pairs[i].y & 255], 1);
    __syncthreads();

    int x = hist[tid], inc = x;
#pragma unroll
    for (int off = 1; off < 64; off <<= 1) {
        int t = __shfl_up(inc, off); if (lane >= off) inc += t;
    }
    if (lane == 63) wsum[wv] = inc;
    __syncthreads();
    if (tid == 0) { int run = 0; for (int i = 0; i < 4; ++i) { int t = wsum[i]; wsum[i] = run; run += t; } }
    __syncthreads();
    int excl = wsum[wv] + inc - x;

    int d = (k << 8) + tid;
    if (d < N) row_start[d] = b0 + excl;
    cur[tid] = b0 + excl;
    __syncthreads();

    for (int i = b0 + tid; i < b1; i += 256) {
        uint2 p = pairs[i];
        int pos = atomicAdd(&cur[p.y & 255], 1);
        ssrc[pos] = (int)p.x;
    }
}

// ---------------- K5: MFMA dual GEMM; h stored fp8 e4m3 (HW cvt) column-strided ----------------
// hb8[row*16 + c16] byte ct = col ct*16+c16.
__global__ __launch_bounds__(256) void matmul_mfma(
    const float* __restrict__ feat, const float* __restrict__ W,
    const float* __restrict__ RW, const float* __restrict__ res_b,
    const int* __restrict__ outcnt,
    unsigned int* __restrict__ hb8, float* __restrict__ y, int N) {
    __shared__ bf16x8 Bf[2048];   // 32 KB
    int tid = threadIdx.x;
    for (int idx = tid; idx < 2048; idx += 256) {
        int mat = idx >> 10;
        int kc = (idx >> 8) & 3;
        int ct = (idx >> 6) & 3;
        int l = idx & 63;
        const float* Wp = mat ? RW : W;
        int kbase = kc * 32 + (l >> 4) * 8;
        int col = ct * 16 + (l & 15);
        bf16x8 t;
#pragma unroll
        for (int j = 0; j < 8; ++j)
            t[j] = (short)f2bf(Wp[(size_t)(kbase + j) * NCOL + col]);
        Bf[idx] = t;
    }
    __syncthreads();

    int lane = tid & 63;
    int wid = tid >> 6;
    int wave = blockIdx.x * 4 + wid;
    int nwaves = gridDim.x * 4;
    int ntiles = (N + 15) >> 4;
    int c16 = lane & 15, kg = lane >> 4;

    float rbv[4];
#pragma unroll
    for (int ct = 0; ct < 4; ++ct) rbv[ct] = res_b[ct * 16 + c16];

    for (int tile = wave; tile < ntiles; tile += nwaves) {
        int tb = tile << 4;
        f32x4 acch[4], accr[4];
#pragma unroll
        for (int ct = 0; ct < 4; ++ct) {
            acch[ct] = (f32x4){0.f, 0.f, 0.f, 0.f};
            accr[ct] = (f32x4){0.f, 0.f, 0.f, 0.f};
        }

        int arow = tb + c16; if (arow >= N) arow = N - 1;
        const float* fp = feat + (size_t)arow * KDIM + kg * 8;
#pragma unroll
        for (int kc = 0; kc < 4; ++kc) {
            float4 a0 = *(const float4*)(fp + kc * 32);
            float4 a1 = *(const float4*)(fp + kc * 32 + 4);
            bf16x8 af;
            af[0] = (short)f2bf(a0.x); af[1] = (short)f2bf(a0.y);
            af[2] = (short)f2bf(a0.z); af[3] = (short)f2bf(a0.w);
            af[4] = (short)f2bf(a1.x); af[5] = (short)f2bf(a1.y);
            af[6] = (short)f2bf(a1.z); af[7] = (short)f2bf(a1.w);
#pragma unroll
            for (int ct = 0; ct < 4; ++ct) {
                acch[ct] = __builtin_amdgcn_mfma_f32_16x16x32_bf16(
                    af, Bf[(kc * 4 + ct) * 64 + lane], acch[ct], 0, 0, 0);
                accr[ct] = __builtin_amdgcn_mfma_f32_16x16x32_bf16(
                    af, Bf[1024 + (kc * 4 + ct) * 64 + lane], accr[ct], 0, 0, 0);
            }
        }

        float nrm[4];
#pragma unroll
        for (int r = 0; r < 4; ++r) {
            int rw = tb + kg * 4 + r; if (rw >= N) rw = N - 1;
            nrm[r] = rsqrtf(fmaxf((float)outcnt[rw], 1.0f));
        }
#pragma unroll
        for (int r = 0; r < 4; ++r) {
            int row = tb + kg * 4 + r;
            if (row < N) {
                unsigned int p = 0;
                p = (unsigned int)__builtin_amdgcn_cvt_pk_fp8_f32(
                        acch[0][r] * nrm[r], acch[1][r] * nrm[r], (int)p, false);
                p = (unsigned int)__builtin_amdgcn_cvt_pk_fp8_f32(
                        acch[2][r] * nrm[r], acch[3][r] * nrm[r], (int)p, true);
#pragma unroll
                for (int ct = 0; ct < 4; ++ct)
                    y[(size_t)row * NCOL + ct * 16 + c16] = fmaxf(accr[ct][r] + rbv[ct], 0.0f);
                hb8[(size_t)row * 16 + c16] = p;
            }
        }
    }
}

// ---------------- gather edge-step: 8 edges of one row per invocation ----------------
// lane: e4 = lane>>4 (edge slot 0..3), dw = lane&15 (dword of 64B fp8 row).
#define GATHER_ROW_STEP(eBase, eEnd, A0, A1, A2, A3)                                   \
    {                                                                                   \
        int e0 = (eBase) + e4, e1 = e0 + 4;                                             \
        int i0 = (e0 < (eEnd)) ? ssrc[e0] : -1;                                         \
        int i1 = (e1 < (eEnd)) ? ssrc[e1] : -1;                                         \
        unsigned int v0 = (i0 >= 0) ? hb8[(size_t)i0 * 16 + dw] : 0u;                   \
        unsigned int v1 = (i1 >= 0) ? hb8[(size_t)i1 * 16 + dw] : 0u;                   \
        f32x2 l0 = __builtin_amdgcn_cvt_pk_f32_fp8((int)v0, false);                     \
        f32x2 h0 = __builtin_amdgcn_cvt_pk_f32_fp8((int)v0, true);                      \
        f32x2 l1 = __builtin_amdgcn_cvt_pk_f32_fp8((int)v1, false);                     \
        f32x2 h1 = __builtin_amdgcn_cvt_pk_f32_fp8((int)v1, true);                      \
        A0 += l0[0] + l1[0]; A1 += l0[1] + l1[1];                                       \
        A2 += h0[0] + h1[0]; A3 += h0[1] + h1[1];                                       \
    }

// ---------------- K6: single-pass gather, full-wave vectorized epilogue ----------------
// Edge phase: 2 rows (A,B) per iteration, 4 edge slots each.
// After the butterfly ALL lanes hold A0-3,B0-3; epilogue assigns
// lane = (rowSel=e4>>1, colHalf=e4&1, dw) -> 2 cols per lane, 4 full-wave VMEM per 2 rows.
__global__ __launch_bounds__(256) void gather_kernel(
    const int* __restrict__ row_start, const int* __restrict__ ssrc,
    const unsigned int* __restrict__ hb8, const float* __restrict__ b,
    float* __restrict__ y, float* __restrict__ stats, int N) {
    int tid = threadIdx.x, lane = tid & 63, wid = tid >> 6;
    int e4 = lane >> 4, dw = lane & 15;
    int rowSel = e4 >> 1;
    int colLo = ((e4 & 1) << 5) + dw;      // {dw, 32+dw}
    int wave = blockIdx.x * 4 + wid;
    int nwaves = gridDim.x * 4;

    float bcLo = b[colLo], bcHi = b[colLo + 16];
    float bnLo = 0.f, bnHi = 0.f, bnsqLo = 0.f, bnsqHi = 0.f;

    for (int d0 = wave * 2; d0 < N; d0 += 2 * nwaves) {
        int d1 = d0 + 1;
        int a0 = row_start[d0], a1 = row_start[d0 + 1];
        int b0e = 0, b1e = 0;
        if (d1 < N) { b0e = a1; b1e = row_start[d1 + 1]; }

        float A0 = 0.f, A1 = 0.f, A2 = 0.f, A3 = 0.f;
        float B0 = 0.f, B1 = 0.f, B2 = 0.f, B3 = 0.f;
        int nit = max((a1 - a0 + 7) >> 3, (b1e - b0e + 7) >> 3);
        for (int it = 0; it < nit; ++it) {
            GATHER_ROW_STEP(a0 + it * 8, a1, A0, A1, A2, A3)
            GATHER_ROW_STEP(b0e + it * 8, b1e, B0, B1, B2, B3)
        }

#pragma unroll
        for (int off = 16; off <= 32; off <<= 1) {
            A0 += __shfl_xor(A0, off); A1 += __shfl_xor(A1, off);
            A2 += __shfl_xor(A2, off); A3 += __shfl_xor(A3, off);
            B0 += __shfl_xor(B0, off); B1 += __shfl_xor(B1, off);
            B2 += __shfl_xor(B2, off); B3 += __shfl_xor(B3, off);
        }

        int dd = d0 + rowSel;
        if (dd < N) {
            int deg = rowSel ? (b1e - b0e) : (a1 - a0);
            float nd = rsqrtf(fmaxf((float)deg, 1.0f));
            float vLo = rowSel ? ((e4 & 1) ? B2 : B0) : ((e4 & 1) ? A2 : A0);
            float vHi = rowSel ? ((e4 & 1) ? B3 : B1) : ((e4 & 1) ? A3 : A1);
            float* yp = &y[(size_t)dd * NCOL + colLo];
            float v0 = fmaxf(vLo * nd + bcLo, 0.f) + yp[0];
            float v1 = fmaxf(vHi * nd + bcHi, 0.f) + yp[16];
            yp[0] = v0;
            yp[16] = v1;
            bnLo += v0; bnsqLo += v0 * v0;
            bnHi += v1; bnsqHi += v1 * v1;
        }
    }

    // fold the two rowSel groups (lane XOR 32 flips rowSel, keeps colLo)
    bnLo += __shfl_xor(bnLo, 32); bnsqLo += __shfl_xor(bnsqLo, 32);
    bnHi += __shfl_xor(bnHi, 32); bnsqHi += __shfl_xor(bnsqHi, 32);

    __shared__ float bnred[4][128];
    if (lane < 32) {
        bnred[wid][colLo] = bnLo;
        bnred[wid][colLo + 16] = bnHi;
        bnred[wid][64 + colLo] = bnsqLo;
        bnred[wid][64 + colLo + 16] = bnsqHi;
    }
    __syncthreads();
    if (tid < 128) {
        float v = bnred[0][tid] + bnred[1][tid] + bnred[2][tid] + bnred[3][tid];
        unsafeAtomicAdd(&stats[tid], v);
    }
}

// ---------------- K7: BN scale/shift ----------------
__global__ void bnparam_kernel(const float* __restrict__ gamma, const float* __restrict__ beta,
                               float* __restrict__ stats, float invN) {
    int c = threadIdx.x;
    float mean = stats[c] * invN;
    float var = stats[64 + c] * invN - mean * mean;
    float s = gamma[c] * rsqrtf(var + 1e-5f);
    stats[128 + c] = s;
    stats[192 + c] = beta[c] - mean * s;
}

// ---------------- K8: BN apply (in place, float4) ----------------
__global__ __launch_bounds__(256) void apply_kernel(float* __restrict__ y,
                                                    const float* __restrict__ stats, int total4) {
    int i = blockIdx.x * blockDim.x + threadIdx.x;
    int stride = gridDim.x * blockDim.x;
    float4* y4 = (float4*)y;
    for (; i < total4; i += stride) {
        float4 v = y4[i];
        int cbase = (i & 15) << 2;
        float4 s = *(const float4*)&stats[128 + cbase];
        float4 t = *(const float4*)&stats[192 + cbase];
        v.x = v.x * s.x + t.x;
        v.y = v.y * s.y + t.y;
        v.z = v.z * s.z + t.z;
        v.w = v.w * s.w + t.w;
        y4[i] = v;
    }
}

extern "C" void kernel_launch(void* const* d_in, const int* in_sizes, int n_in,
                              void* d_out, int out_size, void* d_ws, size_t ws_size,
                              hipStream_t stream) {
    const float* feat  = (const float*)d_in[0];
    const int*   src   = (const int*)d_in[1];
    const int*   dst   = (const int*)d_in[2];
    const float* W     = (const float*)d_in[3];
    const float* b     = (const float*)d_in[4];
    const float* RW    = (const float*)d_in[5];
    const float* rb    = (const float*)d_in[6];
    const float* gamma = (const float*)d_in[7];
    const float* beta  = (const float*)d_in[8];

    int N = in_sizes[0] / KDIM;
    int E = in_sizes[1];
    float* out = (float*)d_out;
    int nbuck = (N + 255) >> 8;   // assumes N <= 131072

    // workspace layout
    char* wsb = (char*)d_ws;
    unsigned int* hb8 = (unsigned int*)wsb;                wsb += (size_t)N * 16 * 4;
    uint2* pairs    = (uint2*)wsb;                         wsb += (size_t)E * 8;
    int*   ssrc     = (int*)wsb;                           wsb += (size_t)E * 4;
    int*   row_start= (int*)wsb;                           wsb += (size_t)(N + 1) * 4;
    int*   outcnt   = (int*)wsb;                           wsb += (size_t)N * 4;
    float* stats    = (float*)wsb;                         wsb += 256 * 4;
    int*   bcnt     = (int*)wsb;                           wsb += NB * 4;
    int*   bbase    = (int*)wsb;                           wsb += NB * 4;
    int*   bcur     = (int*)wsb;

    // zero outcnt | stats | bcnt (contiguous)
    hipMemsetAsync(outcnt, 0, ((size_t)N + 256 + NB) * 4, stream);

    coarse_hist<<<1024, 256, 0, stream>>>(src, dst, outcnt, bcnt, E);
    bucket_scan<<<1, 256, 0, stream>>>(bcnt, bbase, bcur, row_start, N, E);
    matmul_mfma<<<512, 256, 0, stream>>>(feat, W, RW, rb, outcnt, hb8, out, N);
    partition_kernel<<<(E + CH - 1) / CH, 256, 0, stream>>>(src, dst, bcur, pairs, E);
    fine_kernel<<<nbuck, 256, 0, stream>>>(pairs, bbase, row_start, ssrc, E, nbuck, N);
    gather_kernel<<<2048, 256, 0, stream>>>(row_start, ssrc, hb8, b, out, stats, N);
    bnparam_kernel<<<1, 64, 0, stream>>>(gamma, beta, stats, 1.0f / (float)N);
    apply_kernel<<<2048, 256, 0, stream>>>(out, stats, (N * NCOL) / 4);
}